// Round 10
// baseline (199.767 us; speedup 1.0000x reference)
//
#include <hip/hip_runtime.h>
#include <hip/hip_fp16.h>

// Precoding GNN: 5 layers of z = Ws*x + Wm*(sum_k x) + Wk*(sum_m x), ReLU(1-4),
// then Frobenius power normalization per batch item.
// M=64 antennas, K=32 users, D=32 hidden, BS=1024. One 1024-thread block/item.
//
// R21 (117.5us): conflicts EXACTLY unchanged (4.65M) -> L1/L5 were never the
//   conflict source. Pipes: LDS ~52-58%, VALU 48%, MFMA 5% -> phase-limited,
//   occupancy pinned by 128KiB Xs. Remaining lever: LDS-op count in main.
// R22: register-resident X + Bk hoist (bit-identical numerics):
//  * Key identity: thread (w,quad,col)'s B-frag READ set in main(L+1) ==
//    its own WRITE set from main(L) (nodes (w+16i)*16+col, chunk quad).
//    So X lives in xreg[8] across layers; mains 3,4 skip the 8 b128 B-frag
//    reads/thread. Xs writes kept (msgm + L5 still read Xs).
//  * Bk = AB4[(64+16(w&1)+col)*5+quad] is i-invariant -> hoisted (8 reads->1).
//  * Main loop fully unrolled (rule #20: xreg indices compile-time).
//  -16-23 b128 wave-instrs/thread across mains 3,4. VGPR ~56->~100 (still
//  4 waves/SIMD). Numerics: xreg value == the bits that would be re-read ->
//  absmax expected EXACTLY 2.441e-4.

namespace {

constexpr int NTHREADS = 1024;
constexpr float INPUT_SCALE = 0.0625f;      // 2^-4 exact
constexpr float LAYER_SCALE = 0.0078125f;   // 2^-7 exact, folded into W frags

typedef _Float16 half8 __attribute__((ext_vector_type(8)));
typedef _Float16 half2v __attribute__((ext_vector_type(2)));
typedef float    f32x4 __attribute__((ext_vector_type(4)));
typedef unsigned uint4v __attribute__((ext_vector_type(4)));

// AB buffer: 96 rows x 20 dwords. Quad q's uint4 = halves [4q..4q+3, 16+4q..+3].
#define AB_OFF(h) ((((h) >> 2) & 3) * 8 + (((h) >> 4) & 1) * 4 + ((h) & 3))
// Feature-pair stored in slot s of a row: P(s) = 2*(s>>2) + 8*((s>>1)&1) + (s&1)
#define PSLOT(s) (2 * ((s) >> 2) + 8 * (((s) >> 1) & 1) + ((s) & 1))

// MSGK: 8 partial sets, dense 16-dword rows, XOR-swizzled chunk position.
__device__ __forceinline__ int msgk_off(int set, int k, int chunk) {
    return set * 512 + k * 16 + ((chunk ^ ((k >> 1) & 3)) << 2);
}
// MSGM: 2 partial sets (k3 quads {0-3}/{4-7}) x 64 m, dense 16-dword rows.
__device__ __forceinline__ int msgm_off(int row, int chunk) {
    return row * 16 + ((chunk ^ ((row >> 1) & 3)) << 2);
}

__device__ __forceinline__ float2 upk(unsigned w) {
    __half2 h;
    *reinterpret_cast<unsigned*>(&h) = w;
    return __half22float2(h);
}
__device__ __forceinline__ unsigned pkz(float a, float b) {   // v_cvt_pkrtz_f16_f32
    auto h = __builtin_amdgcn_cvt_pkrtz(a, b);   // __fp16 ext_vector(2)
    return __builtin_bit_cast(unsigned, h);
}
__device__ __forceinline__ unsigned hadd2u(unsigned a, unsigned b) {  // v_pk_add_f16
    half2v x = __builtin_bit_cast(half2v, a);
    half2v y = __builtin_bit_cast(half2v, b);
    return __builtin_bit_cast(unsigned, x + y);
}
__device__ __forceinline__ unsigned hmax0u(unsigned a) {      // v_pk_max_f16 with 0
    unsigned r;
    asm("v_pk_max_f16 %0, %1, 0" : "=v"(r) : "v"(a));
    return r;
}
// Cross-lane packed-fp16 add via DPP (VALU pipe, no LDS traffic).
// ONLY XOR-symmetric controls: 0xB1 quad_perm xor1, 0x4E quad_perm xor2,
// 0x128 row_ror:8 ((i+8)&15 == i^8, direction-proof).
template <int CTRL>
__device__ __forceinline__ uint4v dpp_hadd(uint4v s) {
    uint4v r;
    r.x = hadd2u(s.x, (unsigned)__builtin_amdgcn_mov_dpp((int)s.x, CTRL, 0xF, 0xF, true));
    r.y = hadd2u(s.y, (unsigned)__builtin_amdgcn_mov_dpp((int)s.y, CTRL, 0xF, 0xF, true));
    r.z = hadd2u(s.z, (unsigned)__builtin_amdgcn_mov_dpp((int)s.z, CTRL, 0xF, 0xF, true));
    r.w = hadd2u(s.w, (unsigned)__builtin_amdgcn_mov_dpp((int)s.w, CTRL, 0xF, 0xF, true));
    return r;
}

// Weight frag, PERMUTED K-order matching the chunk layout: lane (h, quad) gets
// halves [W[h][4q..4q+3], W[h][16+4q..16+4q+3]] * scale (pow2 -> exact fp16).
__device__ __forceinline__ half8 load_wfrag(const float* __restrict__ W, int h, int quad,
                                            float scale) {
    const float4 w0 = *reinterpret_cast<const float4*>(W + h * 32 + quad * 4);
    const float4 w1 = *reinterpret_cast<const float4*>(W + h * 32 + 16 + quad * 4);
    half8 b;
    b[0] = (_Float16)(w0.x * scale); b[1] = (_Float16)(w0.y * scale);
    b[2] = (_Float16)(w0.z * scale); b[3] = (_Float16)(w0.w * scale);
    b[4] = (_Float16)(w1.x * scale); b[5] = (_Float16)(w1.y * scale);
    b[6] = (_Float16)(w1.z * scale); b[7] = (_Float16)(w1.w * scale);
    return b;
}

// L1 element op: mk = pk_add(m-row, k-row) dword (features h0, h0+1);
// add Ws.x terms, relu, scale, pack.
__device__ __forceinline__ unsigned l1_proc(unsigned mk, const float* __restrict__ w1s,
                                            int h0, float xa, float xb) {
    const float2 f = upk(mk);
    const float a0 = f.x + w1s[h0 * 2] * xa + w1s[h0 * 2 + 1] * xb;
    const float a1 = f.y + w1s[h0 * 2 + 2] * xa + w1s[h0 * 2 + 3] * xb;
    return pkz(fmaxf(a0, 0.f) * LAYER_SCALE, fmaxf(a1, 0.f) * LAYER_SCALE);
}

// ---- msg_m, two partial sets (k3 quads {0-3},{4-7}): 8 b128 reads + DPP
//      xor1+xor2; active lanes l&3==0 write set (l>>2)&1.  (R17-proven tree.)
__device__ __forceinline__ void phase_msgm(const unsigned* __restrict__ Xs,
                                           unsigned* __restrict__ MSGM, int t) {
    const int l = t & 63, w = t >> 6;
    const int k3 = l & 7;
    const int chunk = (l >> 3) & 3;
    const int mlow = ((l >> 5) & 1) | ((w & 15) << 1);
    const int chunkp = chunk ^ ((k3 >> 1) & 3);       // j-invariant (4j%4==0)
    const unsigned* p = Xs + mlow * 512 + k3 * 16 + chunkp * 4;
    half8 accA{}, accB{};
#pragma unroll
    for (int j = 0; j < 4; ++j) {                     // k = k3 + 8j
        accA += __builtin_bit_cast(half8, *(const uint4v*)(p + j * 128));
        accB += __builtin_bit_cast(half8, *(const uint4v*)(p + 16384 + j * 128));
    }
    uint4v sA = __builtin_bit_cast(uint4v, accA);
    uint4v sB = __builtin_bit_cast(uint4v, accB);
    sA = dpp_hadd<0xB1>(sA); sA = dpp_hadd<0x4E>(sA);
    sB = dpp_hadd<0xB1>(sB); sB = dpp_hadd<0x4E>(sB);
    if ((l & 3) == 0) {
        const int set = (l >> 2) & 1;                 // k3 quad {0-3} vs {4-7}
        *(uint4v*)(MSGM + msgm_off(mlow + set * 64, chunk)) = sA;       // m
        *(uint4v*)(MSGM + msgm_off(mlow + 32 + set * 64, chunk)) = sB;  // m+32
    }
}

// ---- layer-2-only msg_k read path: 8-node column sums + row_ror:8 combine
//      (i^8, symmetric -> direction-proof), writes quarter-sets 0-3 of MSGK.
__device__ __forceinline__ void phase_msgk2(const unsigned* __restrict__ Xs,
                                            unsigned* __restrict__ MSGK, int t) {
    const int l = t & 63, w = t >> 6;
    const int k3 = l & 7;
    const int k = ((w & 3) << 3) | k3;
    const int chunk = w >> 2;
    const int mo = l >> 3;
    const int chunkp = chunk ^ ((k3 >> 1) & 3);
    const unsigned* p = Xs + mo * 4096 + k * 16 + chunkp * 4;
    half8 acc{};
#pragma unroll
    for (int j = 0; j < 8; ++j)                       // m = mo*8 + j
        acc += __builtin_bit_cast(half8, *(const uint4v*)(p + j * 512));
    uint4v s = __builtin_bit_cast(uint4v, acc);
    s = dpp_hadd<0x128>(s);                           // combine mo bit0 (i^8)
    if ((l & 8) == 0) {
        const int qi = l >> 4;                        // m-quarter -> set
        *(uint4v*)(MSGK + msgk_off(qi, k, chunk)) = s;
    }
}

// ---- phase B: A-part 2 accumulating MFMAs (msg_m sets); B-part NSETS
//      accumulating MFMAs over MSGK partial sets.
template <int NSETS>
__device__ __forceinline__ void phase_small(const float* __restrict__ Wmg,
                                            const float* __restrict__ Wkg,
                                            const unsigned* __restrict__ MSGM,
                                            const unsigned* __restrict__ MSGK,
                                            unsigned* __restrict__ ABu, int t) {
    const int w = t >> 6, lane = t & 63;
    if (w < 12) {
        const int isb = (w >= 8);
        const int ww = isb ? (w - 8) : w;
        const int nt = ww >> 1, ht = ww & 1;
        const int quad = lane >> 4, col = lane & 15;
        const half8 afrag = load_wfrag(isb ? Wkg : Wmg, ht * 16 + col, quad, LAYER_SCALE);
        f32x4 c = {0.f, 0.f, 0.f, 0.f};
        if (isb) {
            const int kk = nt * 16 + col;
            const unsigned* bp = MSGK + msgk_off(0, kk, quad);
#pragma unroll
            for (int s = 0; s < NSETS; ++s) {
                const half8 bf = __builtin_bit_cast(half8, *(const uint4v*)(bp + s * 512));
                c = __builtin_amdgcn_mfma_f32_16x16x32_f16(afrag, bf, c, 0, 0, 0);
            }
        } else {
            const int r0 = nt * 16 + col;
#pragma unroll
            for (int s = 0; s < 2; ++s) {
                const half8 bf = __builtin_bit_cast(half8,
                    *(const uint4v*)(MSGM + msgm_off(r0 + s * 64, quad)));
                c = __builtin_amdgcn_mfma_f32_16x16x32_f16(afrag, bf, c, 0, 0, 0);
            }
        }
        uint2 st;
        st.x = pkz(c[0], c[1]);
        st.y = pkz(c[2], c[3]);
        const int abrow = (isb ? 64 : 0) + nt * 16 + col;
        *reinterpret_cast<uint2*>(ABu + abrow * 20 + quad * 4 + ht * 2) = st;
    }
}

// ---- phase C: D = Ws_tile x X_group^T; B-frag from Xs (READX, layer 2) or
//      from xreg (layers 3,4 -- thread's read set == its own prior write set,
//      bit-identical). Bk hoisted (i-invariant). Writes Xs (msgm/L5 readers),
//      updates xreg, accumulates register msg_k partial -> MSGK[set = w>>1].
template <bool READX>
__device__ __forceinline__ void phase_main(const float* __restrict__ Wsg,
                                           unsigned* __restrict__ Xs,
                                           const unsigned* __restrict__ ABu,
                                           unsigned* __restrict__ MSGK, int t,
                                           uint4v (&xreg)[8]) {
    const int w = t >> 6, lane = t & 63;
    const int quad = lane >> 4, col = lane & 15;
    const half8 a0 = load_wfrag(Wsg, col, quad, LAYER_SCALE);        // h = col
    const half8 a1 = load_wfrag(Wsg, 16 + col, quad, LAYER_SCALE);   // h = col+16
    const uint4v* AB4 = reinterpret_cast<const uint4v*>(ABu);        // stride 5 uint4
    unsigned* xp = Xs + col * 16 + ((quad ^ ((col >> 1) & 3)) << 2); // swizzled chunk
    const int krow = 64 + ((w & 1) << 4) + col;      // i-invariant (T&1 == w&1)
    const uint4v Bk = AB4[krow * 5 + quad];          // hoisted: 1 read, was 8
    uint4v msgp = {0u, 0u, 0u, 0u};
#pragma unroll
    for (int i = 0; i < 8; ++i) {                    // FULL unroll: xreg[i] static
        const int T = w + i * 16;          // node group T*16..T*16+15
        const int m = T >> 1;
        unsigned* xc = xp + T * 256;
        half8 b;
        if constexpr (READX) {
            const uint4v braw = *(const uint4v*)xc;
            b = __builtin_bit_cast(half8, braw);
        } else {
            b = __builtin_bit_cast(half8, xreg[i]);
        }
        const uint4v Am = AB4[m * 5 + quad];       // broadcast (wave-uniform row)
        const float2 p00 = upk(hadd2u(Am.x, Bk.x));
        const float2 p01 = upk(hadd2u(Am.y, Bk.y));
        const float2 p10 = upk(hadd2u(Am.z, Bk.z));
        const float2 p11 = upk(hadd2u(Am.w, Bk.w));
        f32x4 c0 = {p00.x, p00.y, p01.x, p01.y};
        f32x4 c1 = {p10.x, p10.y, p11.x, p11.y};
        c0 = __builtin_amdgcn_mfma_f32_16x16x32_f16(a0, b, c0, 0, 0, 0);
        c1 = __builtin_amdgcn_mfma_f32_16x16x32_f16(a1, b, c1, 0, 0, 0);
        uint4v st;
        st.x = hmax0u(pkz(c0[0], c0[1]));
        st.y = hmax0u(pkz(c0[2], c0[3]));
        st.z = hmax0u(pkz(c1[0], c1[1]));
        st.w = hmax0u(pkz(c1[2], c1[3]));
        *(uint4v*)xc = st;
        xreg[i] = st;
        msgp.x = hadd2u(msgp.x, st.x);
        msgp.y = hadd2u(msgp.y, st.y);
        msgp.z = hadd2u(msgp.z, st.z);
        msgp.w = hadd2u(msgp.w, st.w);
    }
    const int set = w >> 1;                          // 8 sets over 16 waves
    const int kk = ((w & 1) << 4) | col;             // thread's (shared) k
    *(uint4v*)(MSGK + msgk_off(set, kk, quad)) = msgp;
}

__global__ void __launch_bounds__(NTHREADS) gnn_fused(
    const float* __restrict__ xg,
    const float* __restrict__ w1s, const float* __restrict__ w1m, const float* __restrict__ w1k,
    const float* __restrict__ w2s, const float* __restrict__ w2m, const float* __restrict__ w2k,
    const float* __restrict__ w3s, const float* __restrict__ w3m, const float* __restrict__ w3k,
    const float* __restrict__ w4s, const float* __restrict__ w4m, const float* __restrict__ w4k,
    const float* __restrict__ w5s, const float* __restrict__ w5m, const float* __restrict__ w5k,
    float* __restrict__ out)
{
    __shared__ __align__(16) unsigned Xs[2048 * 16];   // 128 KiB, swizzled rows
    __shared__ __align__(16) unsigned MSGK[8 * 512];   // 16 KiB, 8 partial sets
    __shared__ __align__(16) unsigned MSGM[128 * 16];  // 8 KiB, msg_m 2 sets
    __shared__ __align__(16) unsigned ABu[96 * 20];    // 7.5 KiB
    __shared__ float red[17];

    const int t = threadIdx.x;
    const int b = blockIdx.x;
    const int k = t & 31;
    const int m1 = t >> 5;
    const int m2 = m1 + 32;
    const int lane = t & 63;
    const int wave = t >> 6;
    const int sw1 = (t >> 1) & 3;      // chunk swizzle for nodes t and t+1024

    float2 a1 = *reinterpret_cast<const float2*>(xg + (size_t)b * 4096 + 2 * t);
    float2 a2 = *reinterpret_cast<const float2*>(xg + (size_t)b * 4096 + 2048 + 2 * t);
    a1.x *= INPUT_SCALE; a1.y *= INPUT_SCALE;
    a2.x *= INPUT_SCALE; a2.y *= INPUT_SCALE;

    _Float16* ABf = reinterpret_cast<_Float16*>(ABu);
    float* MSGMf = reinterpret_cast<float*>(MSGM);
    uint4v xreg[8];                    // register-resident X (layers 2->3->4)

    // ================= layer 1 (d_in=2, scalar path) =================
    if (t < 64) MSGMf[t] = 0.f;
    __syncthreads();
    {
        float s0 = a1.x + a2.x, s1 = a1.y + a2.y;
        s0 += __shfl_xor(s0, 32);
        s1 += __shfl_xor(s1, 32);
        if (lane < 32) {
            atomicAdd(&MSGMf[2 * k], s0);
            atomicAdd(&MSGMf[2 * k + 1], s1);
        }
        float f0 = a1.x, f1 = a1.y, g0 = a2.x, g1 = a2.y;
#pragma unroll
        for (int mask = 1; mask <= 16; mask <<= 1) {
            f0 += __shfl_xor(f0, mask); f1 += __shfl_xor(f1, mask);
            g0 += __shfl_xor(g0, mask); g1 += __shfl_xor(g1, mask);
        }
        const float2 wm = *reinterpret_cast<const float2*>(w1m + 2 * k);
        ABf[m1 * 40 + AB_OFF(k)] = (_Float16)(wm.x * f0 + wm.y * f1);
        ABf[m2 * 40 + AB_OFF(k)] = (_Float16)(wm.x * g0 + wm.y * g1);
    }
    __syncthreads();
    {
        const int kk = t >> 5, hh = t & 31;
        const float2 wk2 = *reinterpret_cast<const float2*>(w1k + 2 * hh);
        ABf[(64 + kk) * 40 + AB_OFF(hh)] =
            (_Float16)(wk2.x * MSGMf[2 * kk] + wk2.y * MSGMf[2 * kk + 1]);
    }
    __syncthreads();
    {
        // Vectorized L1 main: k-row once (4 b128, banks 5k mod 8 distinct),
        // m-row per half (broadcast), chunk q out = chunk q in (h0 table).
        const uint4v* krow4 = reinterpret_cast<const uint4v*>(ABu + (64 + k) * 20);
        const uint4v Kq0 = krow4[0], Kq1 = krow4[1], Kq2 = krow4[2], Kq3 = krow4[3];
#pragma unroll 1
        for (int hf = 0; hf < 2; ++hf) {
            const int n = hf ? (t + 1024) : t;
            const int m = hf ? m2 : m1;
            const float xa = hf ? a2.x : a1.x;
            const float xb = hf ? a2.y : a1.y;
            const uint4v* mrow4 = reinterpret_cast<const uint4v*>(ABu + m * 20);
            unsigned* xd = Xs + n * 16;
#define L1Q(q, Kq, H0, H1, H2, H3) { \
            const uint4v Mq = mrow4[q]; \
            uint4v R; \
            R.x = l1_proc(hadd2u(Mq.x, Kq.x), w1s, H0, xa, xb); \
            R.y = l1_proc(hadd2u(Mq.y, Kq.y), w1s, H1, xa, xb); \
            R.z = l1_proc(hadd2u(Mq.z, Kq.z), w1s, H2, xa, xb); \
            R.w = l1_proc(hadd2u(Mq.w, Kq.w), w1s, H3, xa, xb); \
            *(uint4v*)(xd + (((q) ^ sw1) << 2)) = R; }
            L1Q(0, Kq0, 0, 2, 16, 18)
            L1Q(1, Kq1, 4, 6, 20, 22)
            L1Q(2, Kq2, 8, 10, 24, 26)
            L1Q(3, Kq3, 12, 14, 28, 30)
#undef L1Q
        }
    }
    __syncthreads();

    // ================= layers 2-4 (MFMA path) =================
    // layer 2: full msg (read-path msg_k -> sets 0-3, msg_m 2 sets)
    phase_msgk2(Xs, MSGK, t);
    phase_msgm(Xs, MSGM, t); __syncthreads();
    phase_small<4>(w2m, w2k, MSGM, MSGK, ABu, t); __syncthreads();
    phase_main<true>(w2s, Xs, ABu, MSGK, t, xreg); __syncthreads();   // msg_k(X3)

    phase_msgm(Xs, MSGM, t); __syncthreads();
    phase_small<8>(w3m, w3k, MSGM, MSGK, ABu, t); __syncthreads();
    phase_main<false>(w3s, Xs, ABu, MSGK, t, xreg); __syncthreads();  // msg_k(X4)

    phase_msgm(Xs, MSGM, t); __syncthreads();
    phase_small<8>(w4m, w4k, MSGM, MSGK, ABu, t); __syncthreads();
    phase_main<false>(w4s, Xs, ABu, MSGK, t, xreg); __syncthreads();  // msg_k(X5)

    // ================= layer 5 (d_out=2, scalar) =================
    phase_msgm(Xs, MSGM, t); __syncthreads();
    if (t < 128) {                       // A5[m][h] = Wm5[h,:].msg_m[m] (2 sets)
        const int m = t & 63, h = t >> 6;
        const int rot = (m >> 3) & 3;    // bank rotation
        float acc = 0.f;
#pragma unroll
        for (int s0 = 0; s0 < 16; ++s0) {
            const int s = (s0 & 12) | ((s0 + rot) & 3);
            const int pp = PSLOT(s);
            const int idx = msgm_off(m, s >> 2) + (s & 3);
            const float2 uA = upk(MSGM[idx]);            // set 0
            const float2 uB = upk(MSGM[idx + 1024]);     // set 1 (+64 rows)
            acc += w5m[h * 32 + 2 * pp] * (uA.x + uB.x)
                 + w5m[h * 32 + 2 * pp + 1] * (uA.y + uB.y);
        }
        ABf[m * 40 + h] = (_Float16)acc;             // AB_OFF(h)=h for h<4
    } else if (t < 384) {                // B5[k][h] over 8 sets, 4-way split
        const int idx = t - 128;         // 0..255
        const int sp = idx & 3;          // set pair
        const int kk = (idx >> 2) & 31;
        const int h = idx >> 7;          // 0..1
        float acc = 0.f;
#pragma unroll
        for (int s0 = 0; s0 < 16; ++s0) {
            const int s = (s0 & 12) | ((s0 + sp) & 3);   // bank rotation
            const int pp = PSLOT(s);
            const int off = msgk_off(0, kk, s >> 2) + (s & 3);
            const float2 u0 = upk(MSGK[(2 * sp) * 512 + off]);
            const float2 u1 = upk(MSGK[(2 * sp + 1) * 512 + off]);
            acc += w5k[h * 32 + 2 * pp] * (u0.x + u1.x)
                 + w5k[h * 32 + 2 * pp + 1] * (u0.y + u1.y);
        }
        acc += __shfl_xor(acc, 1);
        acc += __shfl_xor(acc, 2);
        if (sp == 0) ABf[(64 + kk) * 40 + h] = (_Float16)acc;
    }
    __syncthreads();

    float za0 = (float)ABf[m1 * 40 + 0] + (float)ABf[(64 + k) * 40 + 0];
    float za1 = (float)ABf[m1 * 40 + 1] + (float)ABf[(64 + k) * 40 + 1];
    float zb0 = (float)ABf[m2 * 40 + 0] + (float)ABf[(64 + k) * 40 + 0];
    float zb1 = (float)ABf[m2 * 40 + 1] + (float)ABf[(64 + k) * 40 + 1];
    {
        const unsigned* xa0 = Xs + t * 16;
        const unsigned* xb0 = xa0 + 16384;           // node t+1024, same sw1
#define L5E(uu, vv, s) { const int pp = PSLOT(s); \
        const float2 u = upk(uu); \
        za0 += w5s[2 * pp] * u.x + w5s[2 * pp + 1] * u.y; \
        za1 += w5s[32 + 2 * pp] * u.x + w5s[32 + 2 * pp + 1] * u.y; \
        const float2 v = upk(vv); \
        zb0 += w5s[2 * pp] * v.x + w5s[2 * pp + 1] * v.y; \
        zb1 += w5s[32 + 2 * pp] * v.x + w5s[32 + 2 * pp + 1] * v.y; }
#define L5C(c, S0) { \
        const uint4v U = *(const uint4v*)(xa0 + (((c) ^ sw1) << 2)); \
        const uint4v V = *(const uint4v*)(xb0 + (((c) ^ sw1) << 2)); \
        L5E(U.x, V.x, S0)     L5E(U.y, V.y, (S0) + 1) \
        L5E(U.z, V.z, (S0) + 2) L5E(U.w, V.w, (S0) + 3) }
        L5C(0, 0) L5C(1, 4) L5C(2, 8) L5C(3, 12)
#undef L5C
#undef L5E
    }

    // ---- pwr_norm (scale-invariant: all per-item multipliers cancel) ----
    float p2 = za0 * za0 + za1 * za1 + zb0 * zb0 + zb1 * zb1;
#pragma unroll
    for (int mask = 1; mask <= 32; mask <<= 1) p2 += __shfl_xor(p2, mask);
    if (lane == 0) red[wave] = p2;
    __syncthreads();
    if (t == 0) {
        float tot = 0.f;
#pragma unroll
        for (int i = 0; i < 16; ++i) tot += red[i];
        red[16] = rsqrtf(tot);
    }
    __syncthreads();
    const float alpha = red[16];

    float2 r1, r2;
    r1.x = alpha * za0; r1.y = alpha * za1;
    r2.x = alpha * zb0; r2.y = alpha * zb1;
    *reinterpret_cast<float2*>(out + (size_t)b * 4096 + 2 * t) = r1;
    *reinterpret_cast<float2*>(out + (size_t)b * 4096 + 2048 + 2 * t) = r2;
}

}  // namespace

extern "C" void kernel_launch(void* const* d_in, const int* in_sizes, int n_in,
                              void* d_out, int out_size, void* d_ws, size_t ws_size,
                              hipStream_t stream) {
    const float* xg  = (const float*)d_in[0];
    const float* w1s = (const float*)d_in[1];
    const float* w1m = (const float*)d_in[2];
    const float* w1k = (const float*)d_in[3];
    const float* w2s = (const float*)d_in[4];
    const float* w2m = (const float*)d_in[5];
    const float* w2k = (const float*)d_in[6];
    const float* w3s = (const float*)d_in[7];
    const float* w3m = (const float*)d_in[8];
    const float* w3k = (const float*)d_in[9];
    const float* w4s = (const float*)d_in[10];
    const float* w4m = (const float*)d_in[11];
    const float* w4k = (const float*)d_in[12];
    const float* w5s = (const float*)d_in[13];
    const float* w5m = (const float*)d_in[14];
    const float* w5k = (const float*)d_in[15];
    float* out = (float*)d_out;

    hipLaunchKernelGGL(gnn_fused, dim3(1024), dim3(NTHREADS), 0, stream,
                       xg, w1s, w1m, w1k, w2s, w2m, w2k, w3s, w3m, w3k,
                       w4s, w4m, w4k, w5s, w5m, w5k, out);
}

// Round 11
// 195.246 us; speedup vs baseline: 1.0232x; 1.0232x over previous
//
#include <hip/hip_runtime.h>
#include <hip/hip_fp16.h>

// Precoding GNN: 5 layers of z = Ws*x + Wm*(sum_k x) + Wk*(sum_m x), ReLU(1-4),
// then Frobenius power normalization per batch item.
// M=64 antennas, K=32 users, D=32 hidden, BS=1024. One 1024-thread block/item.
//
// R22 (118.4us, +1 vs R21): xreg neutral-negative (persistent VGPRs hurt
//   scheduling); conflicts frozen at 4.65M across 3 kernels -> secondary.
//   Pipe budget: VALU-issue 34k cyc + LDS-issue 31k cyc ~= wall 70k (SUM not
//   max: lockstep waves alternate pipe bursts; overlap is poor and the layer
//   dependency chain + 160KB LDS forbid cross-phase wave specialization).
// R23: revert xreg to R21 base; keep Bk hoist (i-invariant, bit-identical,
//   8 reads -> 1); vectorize L5: A5 = 8 b128 (was 32 scalar; octet groups
//   m*4+(c^((m>>1)&3)) all distinct), B5 = 8 b128 with sp-rotated chunk
//   order cc=(c0+sp)&3 (octet sp0-3 x kk0-1 covers all 8 groups).
//   A5/B5 sum reorder = reassociation only.

namespace {

constexpr int NTHREADS = 1024;
constexpr float INPUT_SCALE = 0.0625f;      // 2^-4 exact
constexpr float LAYER_SCALE = 0.0078125f;   // 2^-7 exact, folded into W frags

typedef _Float16 half8 __attribute__((ext_vector_type(8)));
typedef _Float16 half2v __attribute__((ext_vector_type(2)));
typedef float    f32x4 __attribute__((ext_vector_type(4)));
typedef unsigned uint4v __attribute__((ext_vector_type(4)));

// AB buffer: 96 rows x 20 dwords. Quad q's uint4 = halves [4q..4q+3, 16+4q..+3].
#define AB_OFF(h) ((((h) >> 2) & 3) * 8 + (((h) >> 4) & 1) * 4 + ((h) & 3))
// Feature-pair stored in slot s of a row: P(s) = 2*(s>>2) + 8*((s>>1)&1) + (s&1)
#define PSLOT(s) (2 * ((s) >> 2) + 8 * (((s) >> 1) & 1) + ((s) & 1))

// MSGK: 8 partial sets, dense 16-dword rows, XOR-swizzled chunk position.
__device__ __forceinline__ int msgk_off(int set, int k, int chunk) {
    return set * 512 + k * 16 + ((chunk ^ ((k >> 1) & 3)) << 2);
}
// MSGM: 2 partial sets (k3 quads {0-3}/{4-7}) x 64 m, dense 16-dword rows.
__device__ __forceinline__ int msgm_off(int row, int chunk) {
    return row * 16 + ((chunk ^ ((row >> 1) & 3)) << 2);
}

__device__ __forceinline__ float2 upk(unsigned w) {
    __half2 h;
    *reinterpret_cast<unsigned*>(&h) = w;
    return __half22float2(h);
}
__device__ __forceinline__ unsigned pkz(float a, float b) {   // v_cvt_pkrtz_f16_f32
    auto h = __builtin_amdgcn_cvt_pkrtz(a, b);   // __fp16 ext_vector(2)
    return __builtin_bit_cast(unsigned, h);
}
__device__ __forceinline__ unsigned hadd2u(unsigned a, unsigned b) {  // v_pk_add_f16
    half2v x = __builtin_bit_cast(half2v, a);
    half2v y = __builtin_bit_cast(half2v, b);
    return __builtin_bit_cast(unsigned, x + y);
}
__device__ __forceinline__ unsigned hmax0u(unsigned a) {      // v_pk_max_f16 with 0
    unsigned r;
    asm("v_pk_max_f16 %0, %1, 0" : "=v"(r) : "v"(a));
    return r;
}
// Cross-lane packed-fp16 add via DPP (VALU pipe, no LDS traffic).
// ONLY XOR-symmetric controls: 0xB1 quad_perm xor1, 0x4E quad_perm xor2,
// 0x128 row_ror:8 ((i+8)&15 == i^8, direction-proof).
template <int CTRL>
__device__ __forceinline__ uint4v dpp_hadd(uint4v s) {
    uint4v r;
    r.x = hadd2u(s.x, (unsigned)__builtin_amdgcn_mov_dpp((int)s.x, CTRL, 0xF, 0xF, true));
    r.y = hadd2u(s.y, (unsigned)__builtin_amdgcn_mov_dpp((int)s.y, CTRL, 0xF, 0xF, true));
    r.z = hadd2u(s.z, (unsigned)__builtin_amdgcn_mov_dpp((int)s.z, CTRL, 0xF, 0xF, true));
    r.w = hadd2u(s.w, (unsigned)__builtin_amdgcn_mov_dpp((int)s.w, CTRL, 0xF, 0xF, true));
    return r;
}

// Weight frag, PERMUTED K-order matching the chunk layout: lane (h, quad) gets
// halves [W[h][4q..4q+3], W[h][16+4q..16+4q+3]] * scale (pow2 -> exact fp16).
__device__ __forceinline__ half8 load_wfrag(const float* __restrict__ W, int h, int quad,
                                            float scale) {
    const float4 w0 = *reinterpret_cast<const float4*>(W + h * 32 + quad * 4);
    const float4 w1 = *reinterpret_cast<const float4*>(W + h * 32 + 16 + quad * 4);
    half8 b;
    b[0] = (_Float16)(w0.x * scale); b[1] = (_Float16)(w0.y * scale);
    b[2] = (_Float16)(w0.z * scale); b[3] = (_Float16)(w0.w * scale);
    b[4] = (_Float16)(w1.x * scale); b[5] = (_Float16)(w1.y * scale);
    b[6] = (_Float16)(w1.z * scale); b[7] = (_Float16)(w1.w * scale);
    return b;
}

// L1 element op: mk = pk_add(m-row, k-row) dword (features h0, h0+1);
// add Ws.x terms, relu, scale, pack.
__device__ __forceinline__ unsigned l1_proc(unsigned mk, const float* __restrict__ w1s,
                                            int h0, float xa, float xb) {
    const float2 f = upk(mk);
    const float a0 = f.x + w1s[h0 * 2] * xa + w1s[h0 * 2 + 1] * xb;
    const float a1 = f.y + w1s[h0 * 2 + 2] * xa + w1s[h0 * 2 + 3] * xb;
    return pkz(fmaxf(a0, 0.f) * LAYER_SCALE, fmaxf(a1, 0.f) * LAYER_SCALE);
}

// ---- msg_m, two partial sets (k3 quads {0-3},{4-7}): 8 b128 reads + DPP
//      xor1+xor2; active lanes l&3==0 write set (l>>2)&1.  (R17-proven tree.)
__device__ __forceinline__ void phase_msgm(const unsigned* __restrict__ Xs,
                                           unsigned* __restrict__ MSGM, int t) {
    const int l = t & 63, w = t >> 6;
    const int k3 = l & 7;
    const int chunk = (l >> 3) & 3;
    const int mlow = ((l >> 5) & 1) | ((w & 15) << 1);
    const int chunkp = chunk ^ ((k3 >> 1) & 3);       // j-invariant (4j%4==0)
    const unsigned* p = Xs + mlow * 512 + k3 * 16 + chunkp * 4;
    half8 accA{}, accB{};
#pragma unroll
    for (int j = 0; j < 4; ++j) {                     // k = k3 + 8j
        accA += __builtin_bit_cast(half8, *(const uint4v*)(p + j * 128));
        accB += __builtin_bit_cast(half8, *(const uint4v*)(p + 16384 + j * 128));
    }
    uint4v sA = __builtin_bit_cast(uint4v, accA);
    uint4v sB = __builtin_bit_cast(uint4v, accB);
    sA = dpp_hadd<0xB1>(sA); sA = dpp_hadd<0x4E>(sA);
    sB = dpp_hadd<0xB1>(sB); sB = dpp_hadd<0x4E>(sB);
    if ((l & 3) == 0) {
        const int set = (l >> 2) & 1;                 // k3 quad {0-3} vs {4-7}
        *(uint4v*)(MSGM + msgm_off(mlow + set * 64, chunk)) = sA;       // m
        *(uint4v*)(MSGM + msgm_off(mlow + 32 + set * 64, chunk)) = sB;  // m+32
    }
}

// ---- layer-2-only msg_k read path: 8-node column sums + row_ror:8 combine
//      (i^8, symmetric -> direction-proof), writes quarter-sets 0-3 of MSGK.
__device__ __forceinline__ void phase_msgk2(const unsigned* __restrict__ Xs,
                                            unsigned* __restrict__ MSGK, int t) {
    const int l = t & 63, w = t >> 6;
    const int k3 = l & 7;
    const int k = ((w & 3) << 3) | k3;
    const int chunk = w >> 2;
    const int mo = l >> 3;
    const int chunkp = chunk ^ ((k3 >> 1) & 3);
    const unsigned* p = Xs + mo * 4096 + k * 16 + chunkp * 4;
    half8 acc{};
#pragma unroll
    for (int j = 0; j < 8; ++j)                       // m = mo*8 + j
        acc += __builtin_bit_cast(half8, *(const uint4v*)(p + j * 512));
    uint4v s = __builtin_bit_cast(uint4v, acc);
    s = dpp_hadd<0x128>(s);                           // combine mo bit0 (i^8)
    if ((l & 8) == 0) {
        const int qi = l >> 4;                        // m-quarter -> set
        *(uint4v*)(MSGK + msgk_off(qi, k, chunk)) = s;
    }
}

// ---- phase B: A-part 2 accumulating MFMAs (msg_m sets); B-part NSETS
//      accumulating MFMAs over MSGK partial sets.
template <int NSETS>
__device__ __forceinline__ void phase_small(const float* __restrict__ Wmg,
                                            const float* __restrict__ Wkg,
                                            const unsigned* __restrict__ MSGM,
                                            const unsigned* __restrict__ MSGK,
                                            unsigned* __restrict__ ABu, int t) {
    const int w = t >> 6, lane = t & 63;
    if (w < 12) {
        const int isb = (w >= 8);
        const int ww = isb ? (w - 8) : w;
        const int nt = ww >> 1, ht = ww & 1;
        const int quad = lane >> 4, col = lane & 15;
        const half8 afrag = load_wfrag(isb ? Wkg : Wmg, ht * 16 + col, quad, LAYER_SCALE);
        f32x4 c = {0.f, 0.f, 0.f, 0.f};
        if (isb) {
            const int kk = nt * 16 + col;
            const unsigned* bp = MSGK + msgk_off(0, kk, quad);
#pragma unroll
            for (int s = 0; s < NSETS; ++s) {
                const half8 bf = __builtin_bit_cast(half8, *(const uint4v*)(bp + s * 512));
                c = __builtin_amdgcn_mfma_f32_16x16x32_f16(afrag, bf, c, 0, 0, 0);
            }
        } else {
            const int r0 = nt * 16 + col;
#pragma unroll
            for (int s = 0; s < 2; ++s) {
                const half8 bf = __builtin_bit_cast(half8,
                    *(const uint4v*)(MSGM + msgm_off(r0 + s * 64, quad)));
                c = __builtin_amdgcn_mfma_f32_16x16x32_f16(afrag, bf, c, 0, 0, 0);
            }
        }
        uint2 st;
        st.x = pkz(c[0], c[1]);
        st.y = pkz(c[2], c[3]);
        const int abrow = (isb ? 64 : 0) + nt * 16 + col;
        *reinterpret_cast<uint2*>(ABu + abrow * 20 + quad * 4 + ht * 2) = st;
    }
}

// ---- phase C: D = Ws_tile x X_group^T, in-place; Bk hoisted (i-invariant);
//      accumulates register msg_k partial -> MSGK[set = w>>1].
__device__ __forceinline__ void phase_main(const float* __restrict__ Wsg,
                                           unsigned* __restrict__ Xs,
                                           const unsigned* __restrict__ ABu,
                                           unsigned* __restrict__ MSGK, int t) {
    const int w = t >> 6, lane = t & 63;
    const int quad = lane >> 4, col = lane & 15;
    const half8 a0 = load_wfrag(Wsg, col, quad, LAYER_SCALE);        // h = col
    const half8 a1 = load_wfrag(Wsg, 16 + col, quad, LAYER_SCALE);   // h = col+16
    const uint4v* AB4 = reinterpret_cast<const uint4v*>(ABu);        // stride 5 uint4
    unsigned* xp = Xs + col * 16 + ((quad ^ ((col >> 1) & 3)) << 2); // swizzled chunk
    const int krow = 64 + ((w & 1) << 4) + col;      // i-invariant (T&1 == w&1)
    const uint4v Bk = AB4[krow * 5 + quad];          // hoisted: 1 read, was 8
    uint4v msgp = {0u, 0u, 0u, 0u};
#pragma unroll 4
    for (int i = 0; i < 8; ++i) {
        const int T = w + i * 16;          // node group T*16..T*16+15
        const int m = T >> 1;
        unsigned* xc = xp + T * 256;
        const half8 b = __builtin_bit_cast(half8, *(const uint4v*)xc);
        const uint4v Am = AB4[m * 5 + quad];       // broadcast (wave-uniform row)
        const float2 p00 = upk(hadd2u(Am.x, Bk.x));
        const float2 p01 = upk(hadd2u(Am.y, Bk.y));
        const float2 p10 = upk(hadd2u(Am.z, Bk.z));
        const float2 p11 = upk(hadd2u(Am.w, Bk.w));
        f32x4 c0 = {p00.x, p00.y, p01.x, p01.y};
        f32x4 c1 = {p10.x, p10.y, p11.x, p11.y};
        c0 = __builtin_amdgcn_mfma_f32_16x16x32_f16(a0, b, c0, 0, 0, 0);
        c1 = __builtin_amdgcn_mfma_f32_16x16x32_f16(a1, b, c1, 0, 0, 0);
        uint4v st;
        st.x = hmax0u(pkz(c0[0], c0[1]));
        st.y = hmax0u(pkz(c0[2], c0[3]));
        st.z = hmax0u(pkz(c1[0], c1[1]));
        st.w = hmax0u(pkz(c1[2], c1[3]));
        *(uint4v*)xc = st;
        msgp.x = hadd2u(msgp.x, st.x);
        msgp.y = hadd2u(msgp.y, st.y);
        msgp.z = hadd2u(msgp.z, st.z);
        msgp.w = hadd2u(msgp.w, st.w);
    }
    const int set = w >> 1;                          // 8 sets over 16 waves
    const int kk = ((w & 1) << 4) | col;             // thread's (shared) k
    *(uint4v*)(MSGK + msgk_off(set, kk, quad)) = msgp;
}

__global__ void __launch_bounds__(NTHREADS) gnn_fused(
    const float* __restrict__ xg,
    const float* __restrict__ w1s, const float* __restrict__ w1m, const float* __restrict__ w1k,
    const float* __restrict__ w2s, const float* __restrict__ w2m, const float* __restrict__ w2k,
    const float* __restrict__ w3s, const float* __restrict__ w3m, const float* __restrict__ w3k,
    const float* __restrict__ w4s, const float* __restrict__ w4m, const float* __restrict__ w4k,
    const float* __restrict__ w5s, const float* __restrict__ w5m, const float* __restrict__ w5k,
    float* __restrict__ out)
{
    __shared__ __align__(16) unsigned Xs[2048 * 16];   // 128 KiB, swizzled rows
    __shared__ __align__(16) unsigned MSGK[8 * 512];   // 16 KiB, 8 partial sets
    __shared__ __align__(16) unsigned MSGM[128 * 16];  // 8 KiB, msg_m 2 sets
    __shared__ __align__(16) unsigned ABu[96 * 20];    // 7.5 KiB
    __shared__ float red[17];

    const int t = threadIdx.x;
    const int b = blockIdx.x;
    const int k = t & 31;
    const int m1 = t >> 5;
    const int m2 = m1 + 32;
    const int lane = t & 63;
    const int wave = t >> 6;
    const int sw1 = (t >> 1) & 3;      // chunk swizzle for nodes t and t+1024

    float2 a1 = *reinterpret_cast<const float2*>(xg + (size_t)b * 4096 + 2 * t);
    float2 a2 = *reinterpret_cast<const float2*>(xg + (size_t)b * 4096 + 2048 + 2 * t);
    a1.x *= INPUT_SCALE; a1.y *= INPUT_SCALE;
    a2.x *= INPUT_SCALE; a2.y *= INPUT_SCALE;

    _Float16* ABf = reinterpret_cast<_Float16*>(ABu);
    float* MSGMf = reinterpret_cast<float*>(MSGM);

    // ================= layer 1 (d_in=2, scalar path) =================
    if (t < 64) MSGMf[t] = 0.f;
    __syncthreads();
    {
        float s0 = a1.x + a2.x, s1 = a1.y + a2.y;
        s0 += __shfl_xor(s0, 32);
        s1 += __shfl_xor(s1, 32);
        if (lane < 32) {
            atomicAdd(&MSGMf[2 * k], s0);
            atomicAdd(&MSGMf[2 * k + 1], s1);
        }
        float f0 = a1.x, f1 = a1.y, g0 = a2.x, g1 = a2.y;
#pragma unroll
        for (int mask = 1; mask <= 16; mask <<= 1) {
            f0 += __shfl_xor(f0, mask); f1 += __shfl_xor(f1, mask);
            g0 += __shfl_xor(g0, mask); g1 += __shfl_xor(g1, mask);
        }
        const float2 wm = *reinterpret_cast<const float2*>(w1m + 2 * k);
        ABf[m1 * 40 + AB_OFF(k)] = (_Float16)(wm.x * f0 + wm.y * f1);
        ABf[m2 * 40 + AB_OFF(k)] = (_Float16)(wm.x * g0 + wm.y * g1);
    }
    __syncthreads();
    {
        const int kk = t >> 5, hh = t & 31;
        const float2 wk2 = *reinterpret_cast<const float2*>(w1k + 2 * hh);
        ABf[(64 + kk) * 40 + AB_OFF(hh)] =
            (_Float16)(wk2.x * MSGMf[2 * kk] + wk2.y * MSGMf[2 * kk + 1]);
    }
    __syncthreads();
    {
        // Vectorized L1 main: k-row once (4 b128, banks 5k mod 8 distinct),
        // m-row per half (broadcast), chunk q out = chunk q in (h0 table).
        const uint4v* krow4 = reinterpret_cast<const uint4v*>(ABu + (64 + k) * 20);
        const uint4v Kq0 = krow4[0], Kq1 = krow4[1], Kq2 = krow4[2], Kq3 = krow4[3];
#pragma unroll 1
        for (int hf = 0; hf < 2; ++hf) {
            const int n = hf ? (t + 1024) : t;
            const int m = hf ? m2 : m1;
            const float xa = hf ? a2.x : a1.x;
            const float xb = hf ? a2.y : a1.y;
            const uint4v* mrow4 = reinterpret_cast<const uint4v*>(ABu + m * 20);
            unsigned* xd = Xs + n * 16;
#define L1Q(q, Kq, H0, H1, H2, H3) { \
            const uint4v Mq = mrow4[q]; \
            uint4v R; \
            R.x = l1_proc(hadd2u(Mq.x, Kq.x), w1s, H0, xa, xb); \
            R.y = l1_proc(hadd2u(Mq.y, Kq.y), w1s, H1, xa, xb); \
            R.z = l1_proc(hadd2u(Mq.z, Kq.z), w1s, H2, xa, xb); \
            R.w = l1_proc(hadd2u(Mq.w, Kq.w), w1s, H3, xa, xb); \
            *(uint4v*)(xd + (((q) ^ sw1) << 2)) = R; }
            L1Q(0, Kq0, 0, 2, 16, 18)
            L1Q(1, Kq1, 4, 6, 20, 22)
            L1Q(2, Kq2, 8, 10, 24, 26)
            L1Q(3, Kq3, 12, 14, 28, 30)
#undef L1Q
        }
    }
    __syncthreads();

    // ================= layers 2-4 (MFMA path) =================
    // layer 2: full msg (read-path msg_k -> sets 0-3, msg_m 2 sets)
    phase_msgk2(Xs, MSGK, t);
    phase_msgm(Xs, MSGM, t); __syncthreads();
    phase_small<4>(w2m, w2k, MSGM, MSGK, ABu, t); __syncthreads();
    phase_main(w2s, Xs, ABu, MSGK, t); __syncthreads();   // writes msg_k(X3) sets 0-7

    phase_msgm(Xs, MSGM, t); __syncthreads();
    phase_small<8>(w3m, w3k, MSGM, MSGK, ABu, t); __syncthreads();
    phase_main(w3s, Xs, ABu, MSGK, t); __syncthreads();   // writes msg_k(X4)

    phase_msgm(Xs, MSGM, t); __syncthreads();
    phase_small<8>(w4m, w4k, MSGM, MSGK, ABu, t); __syncthreads();
    phase_main(w4s, Xs, ABu, MSGK, t); __syncthreads();   // writes msg_k(X5)

    // ================= layer 5 (d_out=2, scalar) =================
    phase_msgm(Xs, MSGM, t); __syncthreads();
    if (t < 128) {                       // A5[m][h] = Wm5[h,:].msg_m[m] (2 sets)
        const int m = t & 63, h = t >> 6;
        float acc = 0.f;
#pragma unroll
        for (int c = 0; c < 4; ++c) {    // 8 b128 reads (was 32 scalar)
            const int base = msgm_off(m, c);
            const uint4v uA = *(const uint4v*)(MSGM + base);          // set 0
            const uint4v uB = *(const uint4v*)(MSGM + base + 1024);   // set 1
#define A5D(d, word) { const int s = c * 4 + (d); const int pp = PSLOT(s); \
            const float2 fA = upk(uA.word); const float2 fB = upk(uB.word); \
            acc += w5m[h * 32 + 2 * pp] * (fA.x + fB.x) \
                 + w5m[h * 32 + 2 * pp + 1] * (fA.y + fB.y); }
            A5D(0, x) A5D(1, y) A5D(2, z) A5D(3, w)
#undef A5D
        }
        ABf[m * 40 + h] = (_Float16)acc;             // AB_OFF(h)=h for h<4
    } else if (t < 384) {                // B5[k][h] over 8 sets, 4-way split
        const int idx = t - 128;         // 0..255
        const int sp = idx & 3;          // set pair
        const int kk = (idx >> 2) & 31;
        const int h = idx >> 7;          // 0..1
        float acc = 0.f;
#pragma unroll
        for (int c0 = 0; c0 < 4; ++c0) { // 8 b128 reads, sp-rotated chunk order
            const int cc = (c0 + sp) & 3;
            const int base = msgk_off(0, kk, cc);
            const uint4v u0 = *(const uint4v*)(MSGK + (2 * sp) * 512 + base);
            const uint4v u1 = *(const uint4v*)(MSGK + (2 * sp + 1) * 512 + base);
#define B5D(d, word) { const int s = cc * 4 + (d); const int pp = PSLOT(s); \
            const float2 f0 = upk(u0.word); const float2 f1 = upk(u1.word); \
            acc += w5k[h * 32 + 2 * pp] * (f0.x + f1.x) \
                 + w5k[h * 32 + 2 * pp + 1] * (f0.y + f1.y); }
            B5D(0, x) B5D(1, y) B5D(2, z) B5D(3, w)
#undef B5D
        }
        acc += __shfl_xor(acc, 1);
        acc += __shfl_xor(acc, 2);
        if (sp == 0) ABf[(64 + kk) * 40 + h] = (_Float16)acc;
    }
    __syncthreads();

    float za0 = (float)ABf[m1 * 40 + 0] + (float)ABf[(64 + k) * 40 + 0];
    float za1 = (float)ABf[m1 * 40 + 1] + (float)ABf[(64 + k) * 40 + 1];
    float zb0 = (float)ABf[m2 * 40 + 0] + (float)ABf[(64 + k) * 40 + 0];
    float zb1 = (float)ABf[m2 * 40 + 1] + (float)ABf[(64 + k) * 40 + 1];
    {
        const unsigned* xa0 = Xs + t * 16;
        const unsigned* xb0 = xa0 + 16384;           // node t+1024, same sw1
#define L5E(uu, vv, s) { const int pp = PSLOT(s); \
        const float2 u = upk(uu); \
        za0 += w5s[2 * pp] * u.x + w5s[2 * pp + 1] * u.y; \
        za1 += w5s[32 + 2 * pp] * u.x + w5s[32 + 2 * pp + 1] * u.y; \
        const float2 v = upk(vv); \
        zb0 += w5s[2 * pp] * v.x + w5s[2 * pp + 1] * v.y; \
        zb1 += w5s[32 + 2 * pp] * v.x + w5s[32 + 2 * pp + 1] * v.y; }
#define L5C(c, S0) { \
        const uint4v U = *(const uint4v*)(xa0 + (((c) ^ sw1) << 2)); \
        const uint4v V = *(const uint4v*)(xb0 + (((c) ^ sw1) << 2)); \
        L5E(U.x, V.x, S0)     L5E(U.y, V.y, (S0) + 1) \
        L5E(U.z, V.z, (S0) + 2) L5E(U.w, V.w, (S0) + 3) }
        L5C(0, 0) L5C(1, 4) L5C(2, 8) L5C(3, 12)
#undef L5C
#undef L5E
    }

    // ---- pwr_norm (scale-invariant: all per-item multipliers cancel) ----
    float p2 = za0 * za0 + za1 * za1 + zb0 * zb0 + zb1 * zb1;
#pragma unroll
    for (int mask = 1; mask <= 32; mask <<= 1) p2 += __shfl_xor(p2, mask);
    if (lane == 0) red[wave] = p2;
    __syncthreads();
    if (t == 0) {
        float tot = 0.f;
#pragma unroll
        for (int i = 0; i < 16; ++i) tot += red[i];
        red[16] = rsqrtf(tot);
    }
    __syncthreads();
    const float alpha = red[16];

    float2 r1, r2;
    r1.x = alpha * za0; r1.y = alpha * za1;
    r2.x = alpha * zb0; r2.y = alpha * zb1;
    *reinterpret_cast<float2*>(out + (size_t)b * 4096 + 2 * t) = r1;
    *reinterpret_cast<float2*>(out + (size_t)b * 4096 + 2048 + 2 * t) = r2;
}

}  // namespace

extern "C" void kernel_launch(void* const* d_in, const int* in_sizes, int n_in,
                              void* d_out, int out_size, void* d_ws, size_t ws_size,
                              hipStream_t stream) {
    const float* xg  = (const float*)d_in[0];
    const float* w1s = (const float*)d_in[1];
    const float* w1m = (const float*)d_in[2];
    const float* w1k = (const float*)d_in[3];
    const float* w2s = (const float*)d_in[4];
    const float* w2m = (const float*)d_in[5];
    const float* w2k = (const float*)d_in[6];
    const float* w3s = (const float*)d_in[7];
    const float* w3m = (const float*)d_in[8];
    const float* w3k = (const float*)d_in[9];
    const float* w4s = (const float*)d_in[10];
    const float* w4m = (const float*)d_in[11];
    const float* w4k = (const float*)d_in[12];
    const float* w5s = (const float*)d_in[13];
    const float* w5m = (const float*)d_in[14];
    const float* w5k = (const float*)d_in[15];
    float* out = (float*)d_out;

    hipLaunchKernelGGL(gnn_fused, dim3(1024), dim3(NTHREADS), 0, stream,
                       xg, w1s, w1m, w1k, w2s, w2m, w2k, w3s, w3m, w3k,
                       w4s, w4m, w4k, w5s, w5m, w5k, out);
}

// Round 12
// 194.399 us; speedup vs baseline: 1.0276x; 1.0044x over previous
//
#include <hip/hip_runtime.h>
#include <hip/hip_fp16.h>

// Precoding GNN: 5 layers of z = Ws*x + Wm*(sum_k x) + Wk*(sum_m x), ReLU(1-4),
// then Frobenius power normalization per batch item.
// M=64 antennas, K=32 users, D=32 hidden, BS=1024. One 1024-thread block/item.
//
// R23 (115.2us, best): Bk hoist + L5 b128 vectorization landed as modeled.
//   VALU 48.5% / LDS ~40% / MFMA 5% -- no saturated pipe; wall ~= sum of
//   pipe bursts across 14 lockstep barriers at 1 block/CU (Xs=128KB pins
//   occupancy; X-spill to HBM would cost ~125us of traffic).
// R24: cut the f32 C-init in phase_main. relu(WsX+Am+Bk) computed as
//   hmax0(pkz(WsX) +fp16 (Am+Bk)): MFMA runs with C=0 (hoisted), bias added
//   post-MFMA in packed fp16. Deletes 8 v_cvt_f32_f16/iter (192/thread) and
//   unhooks the MFMA from the Am/Bk load+add dependency. Numerics: one extra
//   fp16 rounding on the WsX term -> absmax expected ~4-5e-4 (thr 7.96e-4).
//   msg_k partial still sums the stored values (semantics unchanged).

namespace {

constexpr int NTHREADS = 1024;
constexpr float INPUT_SCALE = 0.0625f;      // 2^-4 exact
constexpr float LAYER_SCALE = 0.0078125f;   // 2^-7 exact, folded into W frags

typedef _Float16 half8 __attribute__((ext_vector_type(8)));
typedef _Float16 half2v __attribute__((ext_vector_type(2)));
typedef float    f32x4 __attribute__((ext_vector_type(4)));
typedef unsigned uint4v __attribute__((ext_vector_type(4)));

// AB buffer: 96 rows x 20 dwords. Quad q's uint4 = halves [4q..4q+3, 16+4q..+3].
#define AB_OFF(h) ((((h) >> 2) & 3) * 8 + (((h) >> 4) & 1) * 4 + ((h) & 3))
// Feature-pair stored in slot s of a row: P(s) = 2*(s>>2) + 8*((s>>1)&1) + (s&1)
#define PSLOT(s) (2 * ((s) >> 2) + 8 * (((s) >> 1) & 1) + ((s) & 1))

// MSGK: 8 partial sets, dense 16-dword rows, XOR-swizzled chunk position.
__device__ __forceinline__ int msgk_off(int set, int k, int chunk) {
    return set * 512 + k * 16 + ((chunk ^ ((k >> 1) & 3)) << 2);
}
// MSGM: 2 partial sets (k3 quads {0-3}/{4-7}) x 64 m, dense 16-dword rows.
__device__ __forceinline__ int msgm_off(int row, int chunk) {
    return row * 16 + ((chunk ^ ((row >> 1) & 3)) << 2);
}

__device__ __forceinline__ float2 upk(unsigned w) {
    __half2 h;
    *reinterpret_cast<unsigned*>(&h) = w;
    return __half22float2(h);
}
__device__ __forceinline__ unsigned pkz(float a, float b) {   // v_cvt_pkrtz_f16_f32
    auto h = __builtin_amdgcn_cvt_pkrtz(a, b);   // __fp16 ext_vector(2)
    return __builtin_bit_cast(unsigned, h);
}
__device__ __forceinline__ unsigned hadd2u(unsigned a, unsigned b) {  // v_pk_add_f16
    half2v x = __builtin_bit_cast(half2v, a);
    half2v y = __builtin_bit_cast(half2v, b);
    return __builtin_bit_cast(unsigned, x + y);
}
__device__ __forceinline__ unsigned hmax0u(unsigned a) {      // v_pk_max_f16 with 0
    unsigned r;
    asm("v_pk_max_f16 %0, %1, 0" : "=v"(r) : "v"(a));
    return r;
}
// Cross-lane packed-fp16 add via DPP (VALU pipe, no LDS traffic).
// ONLY XOR-symmetric controls: 0xB1 quad_perm xor1, 0x4E quad_perm xor2,
// 0x128 row_ror:8 ((i+8)&15 == i^8, direction-proof).
template <int CTRL>
__device__ __forceinline__ uint4v dpp_hadd(uint4v s) {
    uint4v r;
    r.x = hadd2u(s.x, (unsigned)__builtin_amdgcn_mov_dpp((int)s.x, CTRL, 0xF, 0xF, true));
    r.y = hadd2u(s.y, (unsigned)__builtin_amdgcn_mov_dpp((int)s.y, CTRL, 0xF, 0xF, true));
    r.z = hadd2u(s.z, (unsigned)__builtin_amdgcn_mov_dpp((int)s.z, CTRL, 0xF, 0xF, true));
    r.w = hadd2u(s.w, (unsigned)__builtin_amdgcn_mov_dpp((int)s.w, CTRL, 0xF, 0xF, true));
    return r;
}

// Weight frag, PERMUTED K-order matching the chunk layout: lane (h, quad) gets
// halves [W[h][4q..4q+3], W[h][16+4q..16+4q+3]] * scale (pow2 -> exact fp16).
__device__ __forceinline__ half8 load_wfrag(const float* __restrict__ W, int h, int quad,
                                            float scale) {
    const float4 w0 = *reinterpret_cast<const float4*>(W + h * 32 + quad * 4);
    const float4 w1 = *reinterpret_cast<const float4*>(W + h * 32 + 16 + quad * 4);
    half8 b;
    b[0] = (_Float16)(w0.x * scale); b[1] = (_Float16)(w0.y * scale);
    b[2] = (_Float16)(w0.z * scale); b[3] = (_Float16)(w0.w * scale);
    b[4] = (_Float16)(w1.x * scale); b[5] = (_Float16)(w1.y * scale);
    b[6] = (_Float16)(w1.z * scale); b[7] = (_Float16)(w1.w * scale);
    return b;
}

// L1 element op: mk = pk_add(m-row, k-row) dword (features h0, h0+1);
// add Ws.x terms, relu, scale, pack.
__device__ __forceinline__ unsigned l1_proc(unsigned mk, const float* __restrict__ w1s,
                                            int h0, float xa, float xb) {
    const float2 f = upk(mk);
    const float a0 = f.x + w1s[h0 * 2] * xa + w1s[h0 * 2 + 1] * xb;
    const float a1 = f.y + w1s[h0 * 2 + 2] * xa + w1s[h0 * 2 + 3] * xb;
    return pkz(fmaxf(a0, 0.f) * LAYER_SCALE, fmaxf(a1, 0.f) * LAYER_SCALE);
}

// ---- msg_m, two partial sets (k3 quads {0-3},{4-7}): 8 b128 reads + DPP
//      xor1+xor2; active lanes l&3==0 write set (l>>2)&1.  (R17-proven tree.)
__device__ __forceinline__ void phase_msgm(const unsigned* __restrict__ Xs,
                                           unsigned* __restrict__ MSGM, int t) {
    const int l = t & 63, w = t >> 6;
    const int k3 = l & 7;
    const int chunk = (l >> 3) & 3;
    const int mlow = ((l >> 5) & 1) | ((w & 15) << 1);
    const int chunkp = chunk ^ ((k3 >> 1) & 3);       // j-invariant (4j%4==0)
    const unsigned* p = Xs + mlow * 512 + k3 * 16 + chunkp * 4;
    half8 accA{}, accB{};
#pragma unroll
    for (int j = 0; j < 4; ++j) {                     // k = k3 + 8j
        accA += __builtin_bit_cast(half8, *(const uint4v*)(p + j * 128));
        accB += __builtin_bit_cast(half8, *(const uint4v*)(p + 16384 + j * 128));
    }
    uint4v sA = __builtin_bit_cast(uint4v, accA);
    uint4v sB = __builtin_bit_cast(uint4v, accB);
    sA = dpp_hadd<0xB1>(sA); sA = dpp_hadd<0x4E>(sA);
    sB = dpp_hadd<0xB1>(sB); sB = dpp_hadd<0x4E>(sB);
    if ((l & 3) == 0) {
        const int set = (l >> 2) & 1;                 // k3 quad {0-3} vs {4-7}
        *(uint4v*)(MSGM + msgm_off(mlow + set * 64, chunk)) = sA;       // m
        *(uint4v*)(MSGM + msgm_off(mlow + 32 + set * 64, chunk)) = sB;  // m+32
    }
}

// ---- layer-2-only msg_k read path: 8-node column sums + row_ror:8 combine
//      (i^8, symmetric -> direction-proof), writes quarter-sets 0-3 of MSGK.
__device__ __forceinline__ void phase_msgk2(const unsigned* __restrict__ Xs,
                                            unsigned* __restrict__ MSGK, int t) {
    const int l = t & 63, w = t >> 6;
    const int k3 = l & 7;
    const int k = ((w & 3) << 3) | k3;
    const int chunk = w >> 2;
    const int mo = l >> 3;
    const int chunkp = chunk ^ ((k3 >> 1) & 3);
    const unsigned* p = Xs + mo * 4096 + k * 16 + chunkp * 4;
    half8 acc{};
#pragma unroll
    for (int j = 0; j < 8; ++j)                       // m = mo*8 + j
        acc += __builtin_bit_cast(half8, *(const uint4v*)(p + j * 512));
    uint4v s = __builtin_bit_cast(uint4v, acc);
    s = dpp_hadd<0x128>(s);                           // combine mo bit0 (i^8)
    if ((l & 8) == 0) {
        const int qi = l >> 4;                        // m-quarter -> set
        *(uint4v*)(MSGK + msgk_off(qi, k, chunk)) = s;
    }
}

// ---- phase B: A-part 2 accumulating MFMAs (msg_m sets); B-part NSETS
//      accumulating MFMAs over MSGK partial sets.
template <int NSETS>
__device__ __forceinline__ void phase_small(const float* __restrict__ Wmg,
                                            const float* __restrict__ Wkg,
                                            const unsigned* __restrict__ MSGM,
                                            const unsigned* __restrict__ MSGK,
                                            unsigned* __restrict__ ABu, int t) {
    const int w = t >> 6, lane = t & 63;
    if (w < 12) {
        const int isb = (w >= 8);
        const int ww = isb ? (w - 8) : w;
        const int nt = ww >> 1, ht = ww & 1;
        const int quad = lane >> 4, col = lane & 15;
        const half8 afrag = load_wfrag(isb ? Wkg : Wmg, ht * 16 + col, quad, LAYER_SCALE);
        f32x4 c = {0.f, 0.f, 0.f, 0.f};
        if (isb) {
            const int kk = nt * 16 + col;
            const unsigned* bp = MSGK + msgk_off(0, kk, quad);
#pragma unroll
            for (int s = 0; s < NSETS; ++s) {
                const half8 bf = __builtin_bit_cast(half8, *(const uint4v*)(bp + s * 512));
                c = __builtin_amdgcn_mfma_f32_16x16x32_f16(afrag, bf, c, 0, 0, 0);
            }
        } else {
            const int r0 = nt * 16 + col;
#pragma unroll
            for (int s = 0; s < 2; ++s) {
                const half8 bf = __builtin_bit_cast(half8,
                    *(const uint4v*)(MSGM + msgm_off(r0 + s * 64, quad)));
                c = __builtin_amdgcn_mfma_f32_16x16x32_f16(afrag, bf, c, 0, 0, 0);
            }
        }
        uint2 st;
        st.x = pkz(c[0], c[1]);
        st.y = pkz(c[2], c[3]);
        const int abrow = (isb ? 64 : 0) + nt * 16 + col;
        *reinterpret_cast<uint2*>(ABu + abrow * 20 + quad * 4 + ht * 2) = st;
    }
}

// ---- phase C: D = Ws_tile x X_group^T, in-place; Bk hoisted (i-invariant);
//      C=0 MFMA + fp16 post-add of (Am+Bk) (R24); accumulates register msg_k
//      partial -> MSGK[set = w>>1].
__device__ __forceinline__ void phase_main(const float* __restrict__ Wsg,
                                           unsigned* __restrict__ Xs,
                                           const unsigned* __restrict__ ABu,
                                           unsigned* __restrict__ MSGK, int t) {
    const int w = t >> 6, lane = t & 63;
    const int quad = lane >> 4, col = lane & 15;
    const half8 a0 = load_wfrag(Wsg, col, quad, LAYER_SCALE);        // h = col
    const half8 a1 = load_wfrag(Wsg, 16 + col, quad, LAYER_SCALE);   // h = col+16
    const uint4v* AB4 = reinterpret_cast<const uint4v*>(ABu);        // stride 5 uint4
    unsigned* xp = Xs + col * 16 + ((quad ^ ((col >> 1) & 3)) << 2); // swizzled chunk
    const int krow = 64 + ((w & 1) << 4) + col;      // i-invariant (T&1 == w&1)
    const uint4v Bk = AB4[krow * 5 + quad];          // hoisted: 1 read, was 8
    uint4v msgp = {0u, 0u, 0u, 0u};
#pragma unroll 4
    for (int i = 0; i < 8; ++i) {
        const int T = w + i * 16;          // node group T*16..T*16+15
        const int m = T >> 1;
        unsigned* xc = xp + T * 256;
        const half8 b = __builtin_bit_cast(half8, *(const uint4v*)xc);
        const uint4v Am = AB4[m * 5 + quad];       // broadcast (wave-uniform row)
        const unsigned ab0 = hadd2u(Am.x, Bk.x);   // bias, packed fp16
        const unsigned ab1 = hadd2u(Am.y, Bk.y);
        const unsigned ab2 = hadd2u(Am.z, Bk.z);
        const unsigned ab3 = hadd2u(Am.w, Bk.w);
        f32x4 c0 = {0.f, 0.f, 0.f, 0.f};
        f32x4 c1 = {0.f, 0.f, 0.f, 0.f};
        c0 = __builtin_amdgcn_mfma_f32_16x16x32_f16(a0, b, c0, 0, 0, 0);
        c1 = __builtin_amdgcn_mfma_f32_16x16x32_f16(a1, b, c1, 0, 0, 0);
        uint4v st;                                  // relu(pkz(WsX) + (Am+Bk))
        st.x = hmax0u(hadd2u(pkz(c0[0], c0[1]), ab0));
        st.y = hmax0u(hadd2u(pkz(c0[2], c0[3]), ab1));
        st.z = hmax0u(hadd2u(pkz(c1[0], c1[1]), ab2));
        st.w = hmax0u(hadd2u(pkz(c1[2], c1[3]), ab3));
        *(uint4v*)xc = st;
        msgp.x = hadd2u(msgp.x, st.x);
        msgp.y = hadd2u(msgp.y, st.y);
        msgp.z = hadd2u(msgp.z, st.z);
        msgp.w = hadd2u(msgp.w, st.w);
    }
    const int set = w >> 1;                          // 8 sets over 16 waves
    const int kk = ((w & 1) << 4) | col;             // thread's (shared) k
    *(uint4v*)(MSGK + msgk_off(set, kk, quad)) = msgp;
}

__global__ void __launch_bounds__(NTHREADS) gnn_fused(
    const float* __restrict__ xg,
    const float* __restrict__ w1s, const float* __restrict__ w1m, const float* __restrict__ w1k,
    const float* __restrict__ w2s, const float* __restrict__ w2m, const float* __restrict__ w2k,
    const float* __restrict__ w3s, const float* __restrict__ w3m, const float* __restrict__ w3k,
    const float* __restrict__ w4s, const float* __restrict__ w4m, const float* __restrict__ w4k,
    const float* __restrict__ w5s, const float* __restrict__ w5m, const float* __restrict__ w5k,
    float* __restrict__ out)
{
    __shared__ __align__(16) unsigned Xs[2048 * 16];   // 128 KiB, swizzled rows
    __shared__ __align__(16) unsigned MSGK[8 * 512];   // 16 KiB, 8 partial sets
    __shared__ __align__(16) unsigned MSGM[128 * 16];  // 8 KiB, msg_m 2 sets
    __shared__ __align__(16) unsigned ABu[96 * 20];    // 7.5 KiB
    __shared__ float red[17];

    const int t = threadIdx.x;
    const int b = blockIdx.x;
    const int k = t & 31;
    const int m1 = t >> 5;
    const int m2 = m1 + 32;
    const int lane = t & 63;
    const int wave = t >> 6;
    const int sw1 = (t >> 1) & 3;      // chunk swizzle for nodes t and t+1024

    float2 a1 = *reinterpret_cast<const float2*>(xg + (size_t)b * 4096 + 2 * t);
    float2 a2 = *reinterpret_cast<const float2*>(xg + (size_t)b * 4096 + 2048 + 2 * t);
    a1.x *= INPUT_SCALE; a1.y *= INPUT_SCALE;
    a2.x *= INPUT_SCALE; a2.y *= INPUT_SCALE;

    _Float16* ABf = reinterpret_cast<_Float16*>(ABu);
    float* MSGMf = reinterpret_cast<float*>(MSGM);

    // ================= layer 1 (d_in=2, scalar path) =================
    if (t < 64) MSGMf[t] = 0.f;
    __syncthreads();
    {
        float s0 = a1.x + a2.x, s1 = a1.y + a2.y;
        s0 += __shfl_xor(s0, 32);
        s1 += __shfl_xor(s1, 32);
        if (lane < 32) {
            atomicAdd(&MSGMf[2 * k], s0);
            atomicAdd(&MSGMf[2 * k + 1], s1);
        }
        float f0 = a1.x, f1 = a1.y, g0 = a2.x, g1 = a2.y;
#pragma unroll
        for (int mask = 1; mask <= 16; mask <<= 1) {
            f0 += __shfl_xor(f0, mask); f1 += __shfl_xor(f1, mask);
            g0 += __shfl_xor(g0, mask); g1 += __shfl_xor(g1, mask);
        }
        const float2 wm = *reinterpret_cast<const float2*>(w1m + 2 * k);
        ABf[m1 * 40 + AB_OFF(k)] = (_Float16)(wm.x * f0 + wm.y * f1);
        ABf[m2 * 40 + AB_OFF(k)] = (_Float16)(wm.x * g0 + wm.y * g1);
    }
    __syncthreads();
    {
        const int kk = t >> 5, hh = t & 31;
        const float2 wk2 = *reinterpret_cast<const float2*>(w1k + 2 * hh);
        ABf[(64 + kk) * 40 + AB_OFF(hh)] =
            (_Float16)(wk2.x * MSGMf[2 * kk] + wk2.y * MSGMf[2 * kk + 1]);
    }
    __syncthreads();
    {
        // Vectorized L1 main: k-row once (4 b128, banks 5k mod 8 distinct),
        // m-row per half (broadcast), chunk q out = chunk q in (h0 table).
        const uint4v* krow4 = reinterpret_cast<const uint4v*>(ABu + (64 + k) * 20);
        const uint4v Kq0 = krow4[0], Kq1 = krow4[1], Kq2 = krow4[2], Kq3 = krow4[3];
#pragma unroll 1
        for (int hf = 0; hf < 2; ++hf) {
            const int n = hf ? (t + 1024) : t;
            const int m = hf ? m2 : m1;
            const float xa = hf ? a2.x : a1.x;
            const float xb = hf ? a2.y : a1.y;
            const uint4v* mrow4 = reinterpret_cast<const uint4v*>(ABu + m * 20);
            unsigned* xd = Xs + n * 16;
#define L1Q(q, Kq, H0, H1, H2, H3) { \
            const uint4v Mq = mrow4[q]; \
            uint4v R; \
            R.x = l1_proc(hadd2u(Mq.x, Kq.x), w1s, H0, xa, xb); \
            R.y = l1_proc(hadd2u(Mq.y, Kq.y), w1s, H1, xa, xb); \
            R.z = l1_proc(hadd2u(Mq.z, Kq.z), w1s, H2, xa, xb); \
            R.w = l1_proc(hadd2u(Mq.w, Kq.w), w1s, H3, xa, xb); \
            *(uint4v*)(xd + (((q) ^ sw1) << 2)) = R; }
            L1Q(0, Kq0, 0, 2, 16, 18)
            L1Q(1, Kq1, 4, 6, 20, 22)
            L1Q(2, Kq2, 8, 10, 24, 26)
            L1Q(3, Kq3, 12, 14, 28, 30)
#undef L1Q
        }
    }
    __syncthreads();

    // ================= layers 2-4 (MFMA path) =================
    // layer 2: full msg (read-path msg_k -> sets 0-3, msg_m 2 sets)
    phase_msgk2(Xs, MSGK, t);
    phase_msgm(Xs, MSGM, t); __syncthreads();
    phase_small<4>(w2m, w2k, MSGM, MSGK, ABu, t); __syncthreads();
    phase_main(w2s, Xs, ABu, MSGK, t); __syncthreads();   // writes msg_k(X3) sets 0-7

    phase_msgm(Xs, MSGM, t); __syncthreads();
    phase_small<8>(w3m, w3k, MSGM, MSGK, ABu, t); __syncthreads();
    phase_main(w3s, Xs, ABu, MSGK, t); __syncthreads();   // writes msg_k(X4)

    phase_msgm(Xs, MSGM, t); __syncthreads();
    phase_small<8>(w4m, w4k, MSGM, MSGK, ABu, t); __syncthreads();
    phase_main(w4s, Xs, ABu, MSGK, t); __syncthreads();   // writes msg_k(X5)

    // ================= layer 5 (d_out=2, scalar) =================
    phase_msgm(Xs, MSGM, t); __syncthreads();
    if (t < 128) {                       // A5[m][h] = Wm5[h,:].msg_m[m] (2 sets)
        const int m = t & 63, h = t >> 6;
        float acc = 0.f;
#pragma unroll
        for (int c = 0; c < 4; ++c) {    // 8 b128 reads (was 32 scalar)
            const int base = msgm_off(m, c);
            const uint4v uA = *(const uint4v*)(MSGM + base);          // set 0
            const uint4v uB = *(const uint4v*)(MSGM + base + 1024);   // set 1
#define A5D(d, word) { const int s = c * 4 + (d); const int pp = PSLOT(s); \
            const float2 fA = upk(uA.word); const float2 fB = upk(uB.word); \
            acc += w5m[h * 32 + 2 * pp] * (fA.x + fB.x) \
                 + w5m[h * 32 + 2 * pp + 1] * (fA.y + fB.y); }
            A5D(0, x) A5D(1, y) A5D(2, z) A5D(3, w)
#undef A5D
        }
        ABf[m * 40 + h] = (_Float16)acc;             // AB_OFF(h)=h for h<4
    } else if (t < 384) {                // B5[k][h] over 8 sets, 4-way split
        const int idx = t - 128;         // 0..255
        const int sp = idx & 3;          // set pair
        const int kk = (idx >> 2) & 31;
        const int h = idx >> 7;          // 0..1
        float acc = 0.f;
#pragma unroll
        for (int c0 = 0; c0 < 4; ++c0) { // 8 b128 reads, sp-rotated chunk order
            const int cc = (c0 + sp) & 3;
            const int base = msgk_off(0, kk, cc);
            const uint4v u0 = *(const uint4v*)(MSGK + (2 * sp) * 512 + base);
            const uint4v u1 = *(const uint4v*)(MSGK + (2 * sp + 1) * 512 + base);
#define B5D(d, word) { const int s = cc * 4 + (d); const int pp = PSLOT(s); \
            const float2 f0 = upk(u0.word); const float2 f1 = upk(u1.word); \
            acc += w5k[h * 32 + 2 * pp] * (f0.x + f1.x) \
                 + w5k[h * 32 + 2 * pp + 1] * (f0.y + f1.y); }
            B5D(0, x) B5D(1, y) B5D(2, z) B5D(3, w)
#undef B5D
        }
        acc += __shfl_xor(acc, 1);
        acc += __shfl_xor(acc, 2);
        if (sp == 0) ABf[(64 + kk) * 40 + h] = (_Float16)acc;
    }
    __syncthreads();

    float za0 = (float)ABf[m1 * 40 + 0] + (float)ABf[(64 + k) * 40 + 0];
    float za1 = (float)ABf[m1 * 40 + 1] + (float)ABf[(64 + k) * 40 + 1];
    float zb0 = (float)ABf[m2 * 40 + 0] + (float)ABf[(64 + k) * 40 + 0];
    float zb1 = (float)ABf[m2 * 40 + 1] + (float)ABf[(64 + k) * 40 + 1];
    {
        const unsigned* xa0 = Xs + t * 16;
        const unsigned* xb0 = xa0 + 16384;           // node t+1024, same sw1
#define L5E(uu, vv, s) { const int pp = PSLOT(s); \
        const float2 u = upk(uu); \
        za0 += w5s[2 * pp] * u.x + w5s[2 * pp + 1] * u.y; \
        za1 += w5s[32 + 2 * pp] * u.x + w5s[32 + 2 * pp + 1] * u.y; \
        const float2 v = upk(vv); \
        zb0 += w5s[2 * pp] * v.x + w5s[2 * pp + 1] * v.y; \
        zb1 += w5s[32 + 2 * pp] * v.x + w5s[32 + 2 * pp + 1] * v.y; }
#define L5C(c, S0) { \
        const uint4v U = *(const uint4v*)(xa0 + (((c) ^ sw1) << 2)); \
        const uint4v V = *(const uint4v*)(xb0 + (((c) ^ sw1) << 2)); \
        L5E(U.x, V.x, S0)     L5E(U.y, V.y, (S0) + 1) \
        L5E(U.z, V.z, (S0) + 2) L5E(U.w, V.w, (S0) + 3) }
        L5C(0, 0) L5C(1, 4) L5C(2, 8) L5C(3, 12)
#undef L5C
#undef L5E
    }

    // ---- pwr_norm (scale-invariant: all per-item multipliers cancel) ----
    float p2 = za0 * za0 + za1 * za1 + zb0 * zb0 + zb1 * zb1;
#pragma unroll
    for (int mask = 1; mask <= 32; mask <<= 1) p2 += __shfl_xor(p2, mask);
    if (lane == 0) red[wave] = p2;
    __syncthreads();
    if (t == 0) {
        float tot = 0.f;
#pragma unroll
        for (int i = 0; i < 16; ++i) tot += red[i];
        red[16] = rsqrtf(tot);
    }
    __syncthreads();
    const float alpha = red[16];

    float2 r1, r2;
    r1.x = alpha * za0; r1.y = alpha * za1;
    r2.x = alpha * zb0; r2.y = alpha * zb1;
    *reinterpret_cast<float2*>(out + (size_t)b * 4096 + 2 * t) = r1;
    *reinterpret_cast<float2*>(out + (size_t)b * 4096 + 2048 + 2 * t) = r2;
}

}  // namespace

extern "C" void kernel_launch(void* const* d_in, const int* in_sizes, int n_in,
                              void* d_out, int out_size, void* d_ws, size_t ws_size,
                              hipStream_t stream) {
    const float* xg  = (const float*)d_in[0];
    const float* w1s = (const float*)d_in[1];
    const float* w1m = (const float*)d_in[2];
    const float* w1k = (const float*)d_in[3];
    const float* w2s = (const float*)d_in[4];
    const float* w2m = (const float*)d_in[5];
    const float* w2k = (const float*)d_in[6];
    const float* w3s = (const float*)d_in[7];
    const float* w3m = (const float*)d_in[8];
    const float* w3k = (const float*)d_in[9];
    const float* w4s = (const float*)d_in[10];
    const float* w4m = (const float*)d_in[11];
    const float* w4k = (const float*)d_in[12];
    const float* w5s = (const float*)d_in[13];
    const float* w5m = (const float*)d_in[14];
    const float* w5k = (const float*)d_in[15];
    float* out = (float*)d_out;

    hipLaunchKernelGGL(gnn_fused, dim3(1024), dim3(NTHREADS), 0, stream,
                       xg, w1s, w1m, w1k, w2s, w2m, w2k, w3s, w3m, w3k,
                       w4s, w4m, w4k, w5s, w5m, w5k, out);
}